// Round 1
// baseline (186.210 us; speedup 1.0000x reference)
//
#include <hip/hip_runtime.h>
#include <hip/hip_bf16.h>
#include <stdint.h>

typedef __attribute__((ext_vector_type(8))) short bf16x8;
typedef __attribute__((ext_vector_type(4))) short short4v;
typedef __attribute__((ext_vector_type(4))) float f32x4;
typedef __attribute__((ext_vector_type(4))) int int4v;

#define LDS3(p) ((__attribute__((address_space(3))) void*)(p))
#define GLB1(p) ((const __attribute__((address_space(1))) void*)(p))

constexpr int Bc = 4;
constexpr int Cc = 256;   // channels (= d_v)
constexpr int Nn = 4096;  // H*W
constexpr int Dq = 32;    // C/8 (= d_qk)
constexpr float L2E = 1.4426950408889634f;

__device__ __forceinline__ short f2b(float x) {
  union { float f; uint32_t u; } v; v.f = x;
  uint32_t r = (v.u + 0x7fffu + ((v.u >> 16) & 1u)) >> 16;  // RNE
  return (short)(r & 0xffffu);
}

// ---------------------------------------------------------------------------
// Kernel 1: transpose-convert f1/f2 [B][C][N] f32 -> [B][N][C] bf16
// ---------------------------------------------------------------------------
__global__ __launch_bounds__(256) void prep_transpose(
    const float* __restrict__ f1, const float* __restrict__ f2,
    short* __restrict__ f1T, short* __restrict__ f2T) {
  __shared__ float tile[64][65];
  const int bx = blockIdx.x;
  const int which = bx >> 10;          // 0: f1, 1: f2
  const int rem = bx & 1023;
  const int b = rem >> 8;
  const int cb = (rem >> 6) & 3;
  const int nb = rem & 63;
  const float* src = which ? f2 : f1;
  short* dst = which ? f2T : f1T;
  const int c0 = cb * 64, n0 = nb * 64;
  const int tid = threadIdx.x;
  const int lane = tid & 63;
  const int row4 = tid >> 6;
#pragma unroll
  for (int i = 0; i < 16; ++i) {
    const int cl = row4 + i * 4;
    tile[cl][lane] = src[(size_t)(b * Cc + c0 + cl) * Nn + n0 + lane];
  }
  __syncthreads();
#pragma unroll
  for (int i = 0; i < 16; ++i) {
    const int nl = row4 + i * 4;
    dst[(size_t)(b * Nn + n0 + nl) * Cc + c0 + lane] = f2b(tile[lane][nl]);
  }
}

// ---------------------------------------------------------------------------
// Kernel 2: convert weights f32 -> bf16 (layouts preserved: [out][in])
// ---------------------------------------------------------------------------
__global__ __launch_bounds__(256) void prep_weights(
    const float* __restrict__ Wq, const float* __restrict__ Wk,
    const float* __restrict__ Wv, short* __restrict__ Wq_b,
    short* __restrict__ Wk_b, short* __restrict__ Wv_b) {
  const int base = (blockIdx.x * 256 + threadIdx.x) * 4;
#pragma unroll
  for (int j = 0; j < 4; ++j) {
    const int idx = base + j;
    if (idx < 8192) Wq_b[idx] = f2b(Wq[idx]);
    else if (idx < 16384) Wk_b[idx - 8192] = f2b(Wk[idx - 8192]);
    else if (idx < 16384 + 65536) Wv_b[idx - 16384] = f2b(Wv[idx - 16384]);
  }
}

// ---------------------------------------------------------------------------
// Kernel 3: projections via MFMA.
//   q[b][n][o] = sum_c Wq[o][c] f1[b][c][n] + bq[o]   -> q_ws bf16 [B][N][32]
//   k likewise from f2                                -> k_ws bf16 [B][N][32]
//   v[b][c][n] = sum_k Wv[c][k] f2[b][k][n] + bv[c]   -> v_ws bf16 [B][C][N]
// grid = B * N/64 blocks, 256 threads (4 waves).
// ---------------------------------------------------------------------------
__global__ __launch_bounds__(256) void proj_qkv(
    const short* __restrict__ f1T, const short* __restrict__ f2T,
    const short* __restrict__ Wq_b, const float* __restrict__ bq,
    const short* __restrict__ Wk_b, const float* __restrict__ bk,
    const short* __restrict__ Wv_b, const float* __restrict__ bv,
    short* __restrict__ q_ws, short* __restrict__ k_ws,
    short* __restrict__ v_ws) {
  const int bx = blockIdx.x;
  const int b = bx >> 6;
  const int n0 = (bx & 63) * 64;
  const int tid = threadIdx.x;
  const int w = tid >> 6;
  const int lane = tid & 63;
  const int l16 = lane & 15;
  const int g = lane >> 4;

  // ---- Q and K: wave w handles n rows [n0+16w, n0+16w+16)
#pragma unroll
  for (int qk = 0; qk < 2; ++qk) {
    const short* X = qk ? f2T : f1T;
    const short* Wm = qk ? Wk_b : Wq_b;
    const float* bias_p = qk ? bk : bq;
    short* outp = qk ? k_ws : q_ws;
    f32x4 accq[2] = {(f32x4){0.f, 0.f, 0.f, 0.f}, (f32x4){0.f, 0.f, 0.f, 0.f}};
#pragma unroll
    for (int kc = 0; kc < 8; ++kc) {
      const bf16x8 a = *(const bf16x8*)&X[(size_t)(b * Nn + n0 + w * 16 + l16) * Cc + kc * 32 + g * 8];
#pragma unroll
      for (int ob = 0; ob < 2; ++ob) {
        const bf16x8 bb = *(const bf16x8*)&Wm[(ob * 16 + l16) * Cc + kc * 32 + g * 8];
        accq[ob] = __builtin_amdgcn_mfma_f32_16x16x32_bf16(a, bb, accq[ob], 0, 0, 0);
      }
    }
#pragma unroll
    for (int ob = 0; ob < 2; ++ob) {
      const float bias = bias_p[ob * 16 + l16];
#pragma unroll
      for (int r = 0; r < 4; ++r) {
        const int n = n0 + w * 16 + g * 4 + r;
        outp[(size_t)(b * Nn + n) * Dq + ob * 16 + l16] = f2b(accq[ob][r] + bias);
      }
    }
  }

  // ---- V: wave w handles c rows [64w, 64w+64)
  {
    f32x4 acc[4][4];
#pragma unroll
    for (int ci = 0; ci < 4; ++ci)
#pragma unroll
      for (int nb = 0; nb < 4; ++nb) acc[ci][nb] = (f32x4){0.f, 0.f, 0.f, 0.f};
#pragma unroll
    for (int kc = 0; kc < 8; ++kc) {
      bf16x8 bfr[4];
#pragma unroll
      for (int nb = 0; nb < 4; ++nb)
        bfr[nb] = *(const bf16x8*)&f2T[(size_t)(b * Nn + n0 + nb * 16 + l16) * Cc + kc * 32 + g * 8];
#pragma unroll
      for (int ci = 0; ci < 4; ++ci) {
        const bf16x8 afr = *(const bf16x8*)&Wv_b[((w * 4 + ci) * 16 + l16) * Cc + kc * 32 + g * 8];
#pragma unroll
        for (int nb = 0; nb < 4; ++nb)
          acc[ci][nb] = __builtin_amdgcn_mfma_f32_16x16x32_bf16(afr, bfr[nb], acc[ci][nb], 0, 0, 0);
      }
    }
#pragma unroll
    for (int ci = 0; ci < 4; ++ci) {
#pragma unroll
      for (int r = 0; r < 4; ++r) {
        const int c = (w * 4 + ci) * 16 + g * 4 + r;
        const float bias = bv[c];
#pragma unroll
        for (int nb = 0; nb < 4; ++nb) {
          const int n = n0 + nb * 16 + l16;
          v_ws[(size_t)(b * Cc + c) * Nn + n] = f2b(acc[ci][nb][r] + bias);
        }
      }
    }
  }
}

// ---------------------------------------------------------------------------
// Kernel 4: flash attention + epilogue (gamma*attn_out + feat1).
// grid = B * N/64 blocks (64 queries each), 256 threads (4 waves).
// Per key-tile (NT=32): S^T = mfma(K,Q) -> row stats lane-local (row m = l16),
// P staged to padded LDS; V staged via global_load_lds with pre-swizzled
// source (XOR (c&3)<<4); c-split PV across waves; one barrier per tile.
// ---------------------------------------------------------------------------
constexpr int NT = 32;
constexpr int NTILES = Nn / NT;           // 128
constexpr int VBUF = 256 * 64;            // 16 KiB per V buffer
constexpr int VOFF = 0;
constexpr int POFF = 2 * VBUF;            // 32768
constexpr int PBUF = 64 * 80;             // 5120 (padded rows: 64B data + 16B pad)
constexpr int SOFF = POFF + 2 * PBUF;     // 43008 (scales: 2 x 64 f32)
constexpr int FOFF = SOFF + 2 * 256;      // 43520 (flags: 2 x 4 int)
constexpr int LOFF = FOFF + 32;           // 43552 (lrun: 64 f32)
constexpr int SBYTES = LOFF + 256;        // 43808

__global__ __launch_bounds__(256) void attn_kernel(
    const short* __restrict__ q_ws, const short* __restrict__ k_ws,
    const short* __restrict__ v_ws, const float* __restrict__ feat1,
    const float* __restrict__ gamma_p, float* __restrict__ out) {
  __shared__ __align__(16) char smem[SBYTES];
  const int bx = blockIdx.x;
  const int b = bx >> 6;
  const int m0 = (bx & 63) * 64;
  const int tid = threadIdx.x;
  const int w = tid >> 6;
  const int lane = tid & 63;
  const int l16 = lane & 15;
  const int g = lane >> 4;

  // Q as B-operand: col m = l16, k = o = g*8+j  (persist whole kernel)
  const bf16x8 qfrag =
      *(const bf16x8*)&q_ws[(size_t)(b * Nn + m0 + w * 16 + l16) * Dq + g * 8];

  f32x4 acc[4][4];  // O[m = mb*16 + 4g + r][c = 64w + cb*16 + l16]
#pragma unroll
  for (int i = 0; i < 4; ++i)
#pragma unroll
    for (int j = 0; j < 4; ++j) acc[i][j] = (f32x4){0.f, 0.f, 0.f, 0.f};

  float mrun = -INFINITY;
  float lrun = 0.f;

  auto stage = [&](int t, int buf) {
#pragma unroll
    for (int j = 0; j < 4; ++j) {
      const int slot = tid + j * 256;       // 1024 slots of 16B = [256c][4s]
      const int c = slot >> 2;
      const int s = slot & 3;
      // pre-swizzled source so linear LDS-DMA lands swizzled data (rule #21)
      const short* gsrc =
          &v_ws[(size_t)(b * Cc + c) * Nn + t * NT + 8 * (s ^ (c & 3))];
      char* ldst = &smem[VOFF + buf * VBUF + (w * 64 + j * 256) * 16];
      __builtin_amdgcn_global_load_lds(GLB1(gsrc), LDS3(ldst), 16, 0, 0);
    }
  };

  stage(0, 0);
  // K prefetch (tile 0): A-operand rows n = nt0 + 16*nb + l16, k = o
  bf16x8 kf0 = *(const bf16x8*)&k_ws[(size_t)(b * Nn + 0 + l16) * Dq + g * 8];
  bf16x8 kf1 = *(const bf16x8*)&k_ws[(size_t)(b * Nn + 16 + l16) * Dq + g * 8];

  for (int t = 0; t < NTILES; ++t) {
    const int buf = t & 1;
    // ---- S^T = K * Q^T : lane holds S[m=l16][n = t*32 + 16*nb + 4g + r]
    f32x4 s0 = __builtin_amdgcn_mfma_f32_16x16x32_bf16(kf0, qfrag, (f32x4){0.f, 0.f, 0.f, 0.f}, 0, 0, 0);
    f32x4 s1 = __builtin_amdgcn_mfma_f32_16x16x32_bf16(kf1, qfrag, (f32x4){0.f, 0.f, 0.f, 0.f}, 0, 0, 0);

    // ---- online softmax, row m = l16 (reduce across lane groups g)
    float tmax = fmaxf(fmaxf(fmaxf(s0[0], s0[1]), fmaxf(s0[2], s0[3])),
                       fmaxf(fmaxf(s1[0], s1[1]), fmaxf(s1[2], s1[3])));
    tmax = fmaxf(tmax, __shfl_xor(tmax, 16));
    tmax = fmaxf(tmax, __shfl_xor(tmax, 32));
    const int grow = tmax > mrun;
    const float mnew = fmaxf(mrun, tmax);
    float p0[4], p1[4];
    float psum = 0.f;
#pragma unroll
    for (int r = 0; r < 4; ++r) { p0[r] = exp2f((s0[r] - mnew) * L2E); psum += p0[r]; }
#pragma unroll
    for (int r = 0; r < 4; ++r) { p1[r] = exp2f((s1[r] - mnew) * L2E); psum += p1[r]; }
    psum += __shfl_xor(psum, 16);
    psum += __shfl_xor(psum, 32);
    const float scl = (mrun == -INFINITY) ? 0.f : exp2f((mrun - mnew) * L2E);
    lrun = lrun * scl + psum;
    mrun = mnew;

    // ---- write P tile bf16 (rows m = w*16+l16, padded 80B stride)
    short4v pk0, pk1;
#pragma unroll
    for (int r = 0; r < 4; ++r) { pk0[r] = f2b(p0[r]); pk1[r] = f2b(p1[r]); }
    {
      char* prow = &smem[POFF + buf * PBUF + (w * 16 + l16) * 80 + g * 8];
      *(short4v*)(prow + 0) = pk0;   // nb=0: byte col 8g
      *(short4v*)(prow + 32) = pk1;  // nb=1: byte col 32 + 8g
    }
    if (lane < 16) *(float*)&smem[SOFF + buf * 256 + (w * 16 + lane) * 4] = scl;
    const int wgrow = __any(grow);
    if (lane == 0) *(int*)&smem[FOFF + buf * 16 + w * 4] = wgrow;

    asm volatile("s_waitcnt vmcnt(0)" ::: "memory");  // V stage(t) complete
    __syncthreads();

    if (t + 1 < NTILES) {
      stage(t + 1, buf ^ 1);  // overlaps with PV below
      kf0 = *(const bf16x8*)&k_ws[(size_t)(b * Nn + (t + 1) * NT + l16) * Dq + g * 8];
      kf1 = *(const bf16x8*)&k_ws[(size_t)(b * Nn + (t + 1) * NT + 16 + l16) * Dq + g * 8];
    }

    // ---- rescale O only if some row's max grew (block-wide flags)
    const int4v ff = *(const int4v*)&smem[FOFF + buf * 16];
    if (ff.x | ff.y | ff.z | ff.w) {
#pragma unroll
      for (int mb = 0; mb < 4; ++mb) {
#pragma unroll
        for (int r = 0; r < 4; ++r) {
          const float sc = *(const float*)&smem[SOFF + buf * 256 + (mb * 16 + g * 4 + r) * 4];
#pragma unroll
          for (int cb = 0; cb < 4; ++cb) acc[mb][cb][r] *= sc;
        }
      }
    }

    // ---- PV: A = P rows m (all 64), B = V cols c (this wave's 64-slice)
    bf16x8 pA[4], vB[4];
#pragma unroll
    for (int mb = 0; mb < 4; ++mb)
      pA[mb] = *(const bf16x8*)&smem[POFF + buf * PBUF + (mb * 16 + l16) * 80 + g * 16];
#pragma unroll
    for (int cb = 0; cb < 4; ++cb) {
      const int c = w * 64 + cb * 16 + l16;
      vB[cb] = *(const bf16x8*)&smem[VOFF + buf * VBUF + c * 64 + ((g * 16) ^ ((c & 3) << 4))];
    }
#pragma unroll
    for (int mb = 0; mb < 4; ++mb)
#pragma unroll
      for (int cb = 0; cb < 4; ++cb)
        acc[mb][cb] = __builtin_amdgcn_mfma_f32_16x16x32_bf16(pA[mb], vB[cb], acc[mb][cb], 0, 0, 0);
  }

  // ---- epilogue: share lrun, transpose O via LDS, out = gamma*O/l + feat1
  if (lane < 16) *(float*)&smem[LOFF + (w * 16 + lane) * 4] = lrun;
  __syncthreads();
  const float gam = gamma_p[0];
  float* olds = (float*)smem;  // [32 m][257 c] per phase, aliases V/P region
#pragma unroll
  for (int h = 0; h < 2; ++h) {
#pragma unroll
    for (int mb2 = 0; mb2 < 2; ++mb2) {
      const int mb = h * 2 + mb2;
#pragma unroll
      for (int r = 0; r < 4; ++r) {
        const float li = *(const float*)&smem[LOFF + (mb * 16 + g * 4 + r) * 4];
        const float inv = 1.f / li;
#pragma unroll
        for (int cb = 0; cb < 4; ++cb) {
          const int c = w * 64 + cb * 16 + l16;
          olds[(mb2 * 16 + g * 4 + r) * 257 + c] = acc[mb][cb][r] * inv;
        }
      }
    }
    __syncthreads();
    const int mi = tid & 31;
    const int ch = tid >> 5;
#pragma unroll 4
    for (int cc = 0; cc < 32; ++cc) {
      const int c = ch + cc * 8;
      const size_t oi = (size_t)(b * Cc + c) * Nn + m0 + h * 32 + mi;
      out[oi] = gam * olds[mi * 257 + c] + feat1[oi];
    }
    __syncthreads();
  }
}

// ---------------------------------------------------------------------------
// Launch
// ---------------------------------------------------------------------------
extern "C" void kernel_launch(void* const* d_in, const int* in_sizes, int n_in,
                              void* d_out, int out_size, void* d_ws,
                              size_t ws_size, hipStream_t stream) {
  const float* feat1 = (const float*)d_in[0];
  const float* feat2 = (const float*)d_in[1];
  const float* Wq = (const float*)d_in[2];
  const float* bq = (const float*)d_in[3];
  const float* Wk = (const float*)d_in[4];
  const float* bk = (const float*)d_in[5];
  const float* Wv = (const float*)d_in[6];
  const float* bv = (const float*)d_in[7];
  const float* gamma = (const float*)d_in[8];
  float* out = (float*)d_out;

  char* ws = (char*)d_ws;
  short* f1T = (short*)(ws + 0);           //  8 MiB
  short* f2T = (short*)(ws + 8388608);     //  8 MiB
  short* q_ws = (short*)(ws + 16777216);   //  1 MiB
  short* k_ws = (short*)(ws + 17825792);   //  1 MiB
  short* v_ws = (short*)(ws + 18874368);   //  8 MiB
  short* Wq_b = (short*)(ws + 27262976);   // 16 KiB
  short* Wk_b = (short*)(ws + 27279360);   // 16 KiB
  short* Wv_b = (short*)(ws + 27295744);   // 128 KiB

  prep_transpose<<<2048, 256, 0, stream>>>(feat1, feat2, f1T, f2T);
  prep_weights<<<80, 256, 0, stream>>>(Wq, Wk, Wv, Wq_b, Wk_b, Wv_b);
  proj_qkv<<<256, 256, 0, stream>>>(f1T, f2T, Wq_b, bq, Wk_b, bk, Wv_b, bv,
                                    q_ws, k_ws, v_ws);
  attn_kernel<<<256, 256, 0, stream>>>(q_ws, k_ws, v_ws, feat1, gamma, out);
}

// Round 2
// 141.615 us; speedup vs baseline: 1.3149x; 1.3149x over previous
//
#include <hip/hip_runtime.h>
#include <hip/hip_bf16.h>
#include <stdint.h>

typedef __attribute__((ext_vector_type(8))) short bf16x8;
typedef __attribute__((ext_vector_type(4))) short short4v;
typedef __attribute__((ext_vector_type(4))) float f32x4;

#define LDS3(p) ((__attribute__((address_space(3))) void*)(p))
#define GLB1(p) ((const __attribute__((address_space(1))) void*)(p))

constexpr int Bc = 4;
constexpr int Cc = 256;   // channels (= d_v)
constexpr int Nn = 4096;  // H*W
constexpr int Dq = 32;    // C/8 (= d_qk)
constexpr float L2E = 1.4426950408889634f;

__device__ __forceinline__ short f2b(float x) {
  union { float f; uint32_t u; } v; v.f = x;
  uint32_t r = (v.u + 0x7fffu + ((v.u >> 16) & 1u)) >> 16;  // RNE
  return (short)(r & 0xffffu);
}

// ---------------------------------------------------------------------------
// Kernel 1: transpose-convert f1/f2 [B][C][N] f32 -> [B][N][C] bf16
// ---------------------------------------------------------------------------
__global__ __launch_bounds__(256) void prep_transpose(
    const float* __restrict__ f1, const float* __restrict__ f2,
    short* __restrict__ f1T, short* __restrict__ f2T) {
  __shared__ float tile[64][65];
  const int bx = blockIdx.x;
  const int which = bx >> 10;          // 0: f1, 1: f2
  const int rem = bx & 1023;
  const int b = rem >> 8;
  const int cb = (rem >> 6) & 3;
  const int nb = rem & 63;
  const float* src = which ? f2 : f1;
  short* dst = which ? f2T : f1T;
  const int c0 = cb * 64, n0 = nb * 64;
  const int tid = threadIdx.x;
  const int lane = tid & 63;
  const int row4 = tid >> 6;
#pragma unroll
  for (int i = 0; i < 16; ++i) {
    const int cl = row4 + i * 4;
    tile[cl][lane] = src[(size_t)(b * Cc + c0 + cl) * Nn + n0 + lane];
  }
  __syncthreads();
#pragma unroll
  for (int i = 0; i < 16; ++i) {
    const int nl = row4 + i * 4;
    dst[(size_t)(b * Nn + n0 + nl) * Cc + c0 + lane] = f2b(tile[lane][nl]);
  }
}

// ---------------------------------------------------------------------------
// Kernel 2: convert weights f32 -> bf16 (layouts preserved: [out][in])
// ---------------------------------------------------------------------------
__global__ __launch_bounds__(256) void prep_weights(
    const float* __restrict__ Wq, const float* __restrict__ Wk,
    const float* __restrict__ Wv, short* __restrict__ Wq_b,
    short* __restrict__ Wk_b, short* __restrict__ Wv_b) {
  const int base = (blockIdx.x * 256 + threadIdx.x) * 4;
#pragma unroll
  for (int j = 0; j < 4; ++j) {
    const int idx = base + j;
    if (idx < 8192) Wq_b[idx] = f2b(Wq[idx]);
    else if (idx < 16384) Wk_b[idx - 8192] = f2b(Wk[idx - 8192]);
    else if (idx < 16384 + 65536) Wv_b[idx - 16384] = f2b(Wv[idx - 16384]);
  }
}

// ---------------------------------------------------------------------------
// Kernel 3: projections via MFMA (unchanged, known-good).
// ---------------------------------------------------------------------------
__global__ __launch_bounds__(256) void proj_qkv(
    const short* __restrict__ f1T, const short* __restrict__ f2T,
    const short* __restrict__ Wq_b, const float* __restrict__ bq,
    const short* __restrict__ Wk_b, const float* __restrict__ bk,
    const short* __restrict__ Wv_b, const float* __restrict__ bv,
    short* __restrict__ q_ws, short* __restrict__ k_ws,
    short* __restrict__ v_ws) {
  const int bx = blockIdx.x;
  const int b = bx >> 6;
  const int n0 = (bx & 63) * 64;
  const int tid = threadIdx.x;
  const int w = tid >> 6;
  const int lane = tid & 63;
  const int l16 = lane & 15;
  const int g = lane >> 4;

#pragma unroll
  for (int qk = 0; qk < 2; ++qk) {
    const short* X = qk ? f2T : f1T;
    const short* Wm = qk ? Wk_b : Wq_b;
    const float* bias_p = qk ? bk : bq;
    short* outp = qk ? k_ws : q_ws;
    f32x4 accq[2] = {(f32x4){0.f, 0.f, 0.f, 0.f}, (f32x4){0.f, 0.f, 0.f, 0.f}};
#pragma unroll
    for (int kc = 0; kc < 8; ++kc) {
      const bf16x8 a = *(const bf16x8*)&X[(size_t)(b * Nn + n0 + w * 16 + l16) * Cc + kc * 32 + g * 8];
#pragma unroll
      for (int ob = 0; ob < 2; ++ob) {
        const bf16x8 bb = *(const bf16x8*)&Wm[(ob * 16 + l16) * Cc + kc * 32 + g * 8];
        accq[ob] = __builtin_amdgcn_mfma_f32_16x16x32_bf16(a, bb, accq[ob], 0, 0, 0);
      }
    }
#pragma unroll
    for (int ob = 0; ob < 2; ++ob) {
      const float bias = bias_p[ob * 16 + l16];
#pragma unroll
      for (int r = 0; r < 4; ++r) {
        const int n = n0 + w * 16 + g * 4 + r;
        outp[(size_t)(b * Nn + n) * Dq + ob * 16 + l16] = f2b(accq[ob][r] + bias);
      }
    }
  }

  {
    f32x4 acc[4][4];
#pragma unroll
    for (int ci = 0; ci < 4; ++ci)
#pragma unroll
      for (int nb = 0; nb < 4; ++nb) acc[ci][nb] = (f32x4){0.f, 0.f, 0.f, 0.f};
#pragma unroll
    for (int kc = 0; kc < 8; ++kc) {
      bf16x8 bfr[4];
#pragma unroll
      for (int nb = 0; nb < 4; ++nb)
        bfr[nb] = *(const bf16x8*)&f2T[(size_t)(b * Nn + n0 + nb * 16 + l16) * Cc + kc * 32 + g * 8];
#pragma unroll
      for (int ci = 0; ci < 4; ++ci) {
        const bf16x8 afr = *(const bf16x8*)&Wv_b[((w * 4 + ci) * 16 + l16) * Cc + kc * 32 + g * 8];
#pragma unroll
        for (int nb = 0; nb < 4; ++nb)
          acc[ci][nb] = __builtin_amdgcn_mfma_f32_16x16x32_bf16(afr, bfr[nb], acc[ci][nb], 0, 0, 0);
      }
    }
#pragma unroll
    for (int ci = 0; ci < 4; ++ci) {
#pragma unroll
      for (int r = 0; r < 4; ++r) {
        const int c = (w * 4 + ci) * 16 + g * 4 + r;
        const float bias = bv[c];
#pragma unroll
        for (int nb = 0; nb < 4; ++nb) {
          const int n = n0 + nb * 16 + l16;
          v_ws[(size_t)(b * Cc + c) * Nn + n] = f2b(acc[ci][nb][r] + bias);
        }
      }
    }
  }
}

// ---------------------------------------------------------------------------
// Kernel 4: flash attention, ROW-SPLIT waves (wave-local softmax).
// grid = B * N/64 blocks, 4 waves. Wave w owns query rows [w*16, w*16+16)
// and ALL 256 channels. NT=64 keys/tile, V double-buffered in LDS via
// global_load_lds (linear dest, inverse-swizzled source, swizzled read).
// Softmax state fully in-register; defer-max THR=8 (T13) makes the O-rescale
// rare. One barrier per tile (V buffers only).
// ---------------------------------------------------------------------------
constexpr int NT = 64;
constexpr int NTILES = Nn / NT;        // 64
constexpr int VBUF = 256 * NT * 2;     // 32768 B per buffer ([c][key] bf16)
constexpr int POFF = 2 * VBUF;         // 65536; P: 4 waves x 16 rows x 128B
constexpr int SBYTES = POFF + 4 * 2048;  // 73728

__global__ __launch_bounds__(256) void attn_kernel(
    const short* __restrict__ q_ws, const short* __restrict__ k_ws,
    const short* __restrict__ v_ws, const float* __restrict__ feat1,
    const float* __restrict__ gamma_p, float* __restrict__ out) {
  __shared__ __align__(16) char smem[SBYTES];
  const int bx = blockIdx.x;
  const int b = bx >> 6;
  const int m0 = (bx & 63) * 64;
  const int tid = threadIdx.x;
  const int w = tid >> 6;
  const int lane = tid & 63;
  const int l16 = lane & 15;
  const int g = lane >> 4;

  // Q frag (B operand): rows m = m0 + w*16 + l16, k = g*8+j
  const bf16x8 qfrag =
      *(const bf16x8*)&q_ws[(size_t)(b * Nn + m0 + w * 16 + l16) * Dq + g * 8];

  // V stage: thread owns granule (c = j*32 + tid>>3, q = tid&7); source
  // pre-swizzled by q ^= (c&7) so linear LDS-DMA lands the swizzled image.
  const int cth = tid >> 3;
  const int qsw = (tid & 7) ^ (cth & 7);
  const short* vsrc[8];
#pragma unroll
  for (int j = 0; j < 8; ++j)
    vsrc[j] = v_ws + (size_t)(b * Cc + j * 32 + cth) * Nn + qsw * 8;

  const short* kptr = k_ws + (size_t)(b * Nn + l16) * Dq + g * 8;

  f32x4 acc[16];  // O[m_local = 4g+r][c = cb*16 + l16]
#pragma unroll
  for (int i = 0; i < 16; ++i) acc[i] = (f32x4){0.f, 0.f, 0.f, 0.f};

  float mrun = -INFINITY, lrun = 0.f;

  // prologue: stage tile 0, prefetch K(0)
#pragma unroll
  for (int j = 0; j < 8; ++j) {
    char* ldst = &smem[(j * 256 + w * 64) * 16];
    __builtin_amdgcn_global_load_lds(GLB1(vsrc[j]), LDS3(ldst), 16, 0, 0);
    vsrc[j] += NT;
  }
  bf16x8 kf[4];
#pragma unroll
  for (int nb = 0; nb < 4; ++nb)
    kf[nb] = *(const bf16x8*)(kptr + nb * 16 * Dq);
  kptr += NT * Dq;

  const int pbase = POFF + w * 2048 + l16 * 128;
  const int psw = l16 & 7;

  for (int t = 0; t < NTILES; ++t) {
    const int buf = t & 1;
    // ---- S^T = K*Q^T: lane holds S[m=l16][n = t*64 + nb*16 + 4g + r]
    f32x4 s[4];
#pragma unroll
    for (int nb = 0; nb < 4; ++nb)
      s[nb] = __builtin_amdgcn_mfma_f32_16x16x32_bf16(
          kf[nb], qfrag, (f32x4){0.f, 0.f, 0.f, 0.f}, 0, 0, 0);

    // ---- wave-local online softmax (row m = l16; reduce over g)
    float tmax = fmaxf(fmaxf(s[0][0], s[0][1]), fmaxf(s[0][2], s[0][3]));
#pragma unroll
    for (int nb = 1; nb < 4; ++nb)
      tmax = fmaxf(tmax, fmaxf(fmaxf(s[nb][0], s[nb][1]), fmaxf(s[nb][2], s[nb][3])));
    tmax = fmaxf(tmax, __shfl_xor(tmax, 16));
    tmax = fmaxf(tmax, __shfl_xor(tmax, 32));
    if (__any(tmax > mrun + 8.f)) {       // defer-max: rescale rarely
      const float mnew = fmaxf(mrun, tmax);
      const float scl = exp2f((mrun - mnew) * L2E);
      float sc[4];
#pragma unroll
      for (int r = 0; r < 4; ++r) sc[r] = __shfl(scl, (g << 2) | r);
#pragma unroll
      for (int cb = 0; cb < 16; ++cb)
#pragma unroll
        for (int r = 0; r < 4; ++r) acc[cb][r] *= sc[r];
      lrun *= scl;
      mrun = mnew;
    }
    float psum = 0.f;
    short4v pk[4];
#pragma unroll
    for (int nb = 0; nb < 4; ++nb)
#pragma unroll
      for (int r = 0; r < 4; ++r) {
        const float p = exp2f((s[nb][r] - mrun) * L2E);
        psum += p;
        pk[nb][r] = f2b(p);
      }
    psum += __shfl_xor(psum, 16);
    psum += __shfl_xor(psum, 32);
    lrun += psum;

    // ---- P write (wave-private, swizzled 16B granules)
#pragma unroll
    for (int nb = 0; nb < 4; ++nb) {
      const int off = (((nb * 2 + (g >> 1)) ^ psw) << 4) | ((g & 1) << 3);
      *(short4v*)&smem[pbase + off] = pk[nb];
    }

    asm volatile("s_waitcnt vmcnt(0)" ::: "memory");  // own V(t) parts done
    __syncthreads();                                   // all parts visible

    if (t + 1 < NTILES) {
#pragma unroll
      for (int j = 0; j < 8; ++j) {
        char* ldst = &smem[(buf ^ 1) * VBUF + (j * 256 + w * 64) * 16];
        __builtin_amdgcn_global_load_lds(GLB1(vsrc[j]), LDS3(ldst), 16, 0, 0);
        vsrc[j] += NT;
      }
#pragma unroll
      for (int nb = 0; nb < 4; ++nb)
        kf[nb] = *(const bf16x8*)(kptr + nb * 16 * Dq);
      kptr += NT * Dq;
    }

    // ---- PV: A = P[16 rows][64 keys] (2 k-frags), B = V[keys][256 c]
    bf16x8 pA[2];
#pragma unroll
    for (int kk = 0; kk < 2; ++kk)
      pA[kk] = *(const bf16x8*)&smem[pbase + (((kk * 4 + g) ^ psw) << 4)];
#pragma unroll
    for (int kk = 0; kk < 2; ++kk)
#pragma unroll
      for (int cb = 0; cb < 16; ++cb) {
        const int c = cb * 16 + l16;
        const bf16x8 vB = *(const bf16x8*)&smem[buf * VBUF + c * 128 +
                                                (((kk * 4 + g) ^ psw) << 4)];
        acc[cb] = __builtin_amdgcn_mfma_f32_16x16x32_bf16(pA[kk], vB, acc[cb], 0, 0, 0);
      }
  }

  // ---- epilogue: per-wave transpose via LDS, out = gamma*O/l + feat1
  __syncthreads();  // everyone done reading V LDS
  float inv[4];
#pragma unroll
  for (int r = 0; r < 4; ++r) {
    const float lr = __shfl(lrun, (g << 2) | r);  // lrun for row 4g+r
    inv[r] = 1.f / lr;
  }
  float* olds = (float*)&smem[w * 16448];  // [16 m][257 c]
#pragma unroll
  for (int cb = 0; cb < 16; ++cb)
#pragma unroll
    for (int r = 0; r < 4; ++r)
      olds[(4 * g + r) * 257 + cb * 16 + l16] = acc[cb][r] * inv[r];
  asm volatile("s_waitcnt lgkmcnt(0)" ::: "memory");  // wave-local write->read
  const float gam = gamma_p[0];
  const int c4 = lane >> 4;
  const int mm = lane & 15;
  const size_t obase = (size_t)b * Cc * Nn + (size_t)(m0 + w * 16 + mm);
#pragma unroll 8
  for (int cc = 0; cc < 64; ++cc) {
    const int c = cc * 4 + c4;
    const size_t oi = obase + (size_t)c * Nn;
    out[oi] = gam * olds[mm * 257 + c] + feat1[oi];
  }
}

// ---------------------------------------------------------------------------
// Launch
// ---------------------------------------------------------------------------
extern "C" void kernel_launch(void* const* d_in, const int* in_sizes, int n_in,
                              void* d_out, int out_size, void* d_ws,
                              size_t ws_size, hipStream_t stream) {
  const float* feat1 = (const float*)d_in[0];
  const float* feat2 = (const float*)d_in[1];
  const float* Wq = (const float*)d_in[2];
  const float* bq = (const float*)d_in[3];
  const float* Wk = (const float*)d_in[4];
  const float* bk = (const float*)d_in[5];
  const float* Wv = (const float*)d_in[6];
  const float* bv = (const float*)d_in[7];
  const float* gamma = (const float*)d_in[8];
  float* out = (float*)d_out;

  char* ws = (char*)d_ws;
  short* f1T = (short*)(ws + 0);           //  8 MiB
  short* f2T = (short*)(ws + 8388608);     //  8 MiB
  short* q_ws = (short*)(ws + 16777216);   //  1 MiB
  short* k_ws = (short*)(ws + 17825792);   //  1 MiB
  short* v_ws = (short*)(ws + 18874368);   //  8 MiB
  short* Wq_b = (short*)(ws + 27262976);   // 16 KiB
  short* Wk_b = (short*)(ws + 27279360);   // 16 KiB
  short* Wv_b = (short*)(ws + 27295744);   // 128 KiB

  prep_transpose<<<2048, 256, 0, stream>>>(feat1, feat2, f1T, f2T);
  prep_weights<<<80, 256, 0, stream>>>(Wq, Wk, Wv, Wq_b, Wk_b, Wv_b);
  proj_qkv<<<256, 256, 0, stream>>>(f1T, f2T, Wq_b, bq, Wk_b, bk, Wv_b, bv,
                                    q_ws, k_ws, v_ws);
  attn_kernel<<<256, 256, 0, stream>>>(q_ws, k_ws, v_ws, feat1, gamma, out);
}